// Round 2
// baseline (530.338 us; speedup 1.0000x reference)
//
#include <hip/hip_runtime.h>
#include <cstdint>
#include <math.h>

#define K_TOK 2048
#define TPL   32      // tokens per lane (K_TOK / 64)
#define BLK   512
#define WPB   8       // waves (=rows) per block
#define NBIN  128

// monotonic float->uint key (only used in the exact fallback path)
__device__ __forceinline__ uint32_t f2key(float f) {
    uint32_t u = __float_as_uint(f);
    return u ^ ((uint32_t)(((int32_t)u) >> 31) | 0x80000000u);
}

// ---------------- prep kernels ----------------
__global__ void prep_tok(const float* __restrict__ mpt,
                         float4* __restrict__ b4out, float* __restrict__ sbout) {
    #pragma clang fp contract(off)
    int k = blockIdx.x * blockDim.x + threadIdx.x;
    if (k >= K_TOK) return;
    float b0 = mpt[k*6+0], b1 = mpt[k*6+1], b2 = mpt[k*6+2];
    float b3 = mpt[k*6+3], b4 = mpt[k*6+4], b5 = mpt[k*6+5];
    float q0=b0*b0,q1=b1*b1,q2=b2*b2,q3=b3*b3,q4=b4*b4,q5=b5*b5;
    float s = ((((q0+q1)+q2)+q3)+q4)+q5;   // sequential, no fma
    b4out[k] = make_float4(b2,b3,b4,b5);
    sbout[k] = s;
}

// per-row local frame (bit-identical to the in-kernel fallback path)
__global__ void prep_frame(const float* __restrict__ traj_pos,
                           const float* __restrict__ traj_theta,
                           float4* __restrict__ aA, float* __restrict__ saA, int N) {
    #pragma clang fp contract(off)
    int n = blockIdx.x * blockDim.x + threadIdx.x;
    if (n >= N) return;
    const float* tp = traj_pos + (size_t)n*6;
    float p0x=tp[0], p0y=tp[1];
    float dx1=tp[2]-p0x, dy1=tp[3]-p0y;
    float dx2=tp[4]-p0x, dy2=tp[5]-p0y;
    float th = traj_theta[n];
    float c = (float)cos((double)th);   // keep separate cos/sin: bit-match R1
    float s = (float)sin((double)th);
    float ns = -s;
    float a2 = c*dx1 + s*dy1;
    float a3 = ns*dx1 + c*dy1;
    float a4 = c*dx2 + s*dy2;
    float a5 = ns*dx2 + c*dy2;
    float q2=a2*a2,q3=a3*a3,q4=a4*a4,q5=a5*a5;
    float sa = ((q2+q3)+q4)+q5;
    aA[n] = make_float4(a2,a3,a4,a5);
    saA[n] = sa;
}

// per-(row,slot) gumbel noise (bit-identical op sequence to in-kernel path)
__global__ void prep_gumbel(const float* __restrict__ gu, float* __restrict__ g, int total) {
    #pragma clang fp contract(off)
    int i = blockIdx.x * blockDim.x + threadIdx.x;
    if (i >= total) return;
    const float C1F = (float)(1.0 - 2.0*1e-7);
    float u = gu[i];
    float t = u * C1F;
    t = t + 1e-7f;
    float li = (float)log((double)t);
    float ni = -li;
    float lo = (float)log((double)ni);
    g[i] = -lo;
}

// ---------------- main kernel ----------------
__global__ __launch_bounds__(BLK) void topk_kernel(
        const float* __restrict__ traj_pos, const float* __restrict__ traj_theta,
        const float4* __restrict__ b4g, const float* __restrict__ sbg,
        const float4* __restrict__ aAg, const float* __restrict__ saAg,
        const float* __restrict__ gtab,
        const float* __restrict__ token_src, const float* __restrict__ gumbel,
        float* __restrict__ out, int Nrows, int useFrame, int useG) {
    #pragma clang fp contract(off)
    __shared__ float4   sB4[K_TOK];
    __shared__ float    sSB[K_TOK];
    __shared__ uint32_t sHist[WPB][NBIN];
    __shared__ uint64_t sC[WPB][64];

    const int tid = threadIdx.x;
    for (int t = tid; t < K_TOK; t += BLK) { sB4[t] = b4g[t]; sSB[t] = sbg[t]; }
    __syncthreads();

    const int wv   = tid >> 6;
    const int lane = tid & 63;
    const int n    = blockIdx.x * WPB + wv;
    if (n >= Nrows) return;

    // ---- per-row local frame
    float a2, a3, a4, a5, sa;
    if (useFrame) {
        float4 av = aAg[n];
        a2 = av.x; a3 = av.y; a4 = av.z; a5 = av.w;
        sa = saAg[n];
    } else {
        const float* tp = traj_pos + (size_t)n * 6;
        float p0x = tp[0], p0y = tp[1];
        float dx1 = tp[2] - p0x, dy1 = tp[3] - p0y;
        float dx2 = tp[4] - p0x, dy2 = tp[5] - p0y;
        float th = traj_theta[n];
        float c = (float)cos((double)th);
        float s = (float)sin((double)th);
        float ns = -s;
        a2 = c*dx1 + s*dy1;
        a3 = ns*dx1 + c*dy1;
        a4 = c*dx2 + s*dy2;
        a5 = ns*dx2 + c*dy2;
        float q2 = a2*a2, q3 = a3*a3, q4 = a4*a4, q5 = a5*a5;
        sa = ((q2 + q3) + q4) + q5;
    }

    // ---- distances (exact reference rounding), plus per-lane min
    float dd[TPL];
    float lmin;
    #pragma unroll
    for (int j = 0; j < TPL; ++j) {
        int t = j * 64 + lane;
        float4 b = sB4[t];
        float sbv = sSB[t];
        float d0 = a2 * b.x;
        d0 = fmaf(a3, b.y, d0);
        d0 = fmaf(a4, b.z, d0);
        d0 = fmaf(a5, b.w, d0);
        float t2 = 2.0f * d0;
        float dist = (sa + sbv) - t2;
        dd[j] = dist;
        lmin = (j == 0) ? dist : fminf(lmin, dist);
    }

    // ---- wave-global min (gmn) and max of lane-minima (gmx).
    // The 32nd smallest of all 2048 lies in [gmn, gmx]: each of the 64 lanes
    // contributes one value <= gmx, so count(d <= gmx) >= 64 >= 32.
    float gmn = lmin, gmx = lmin;
    #pragma unroll
    for (int m2 = 1; m2 < 64; m2 <<= 1) {
        float og = __shfl_xor(gmn, m2, 64);
        float ox = __shfl_xor(gmx, m2, 64);
        gmn = fminf(gmn, og);
        gmx = fmaxf(gmx, ox);
    }

    // ---- histogram-refinement selection of threshold with count in [32,64]
    uint32_t m_eq = 0xFFFFFFFFu, m_less = 0u;
    int   c_less = 0;
    float lo = gmn, width = gmx - gmn;
    float fin_lo = 0.f, fin_scale = 0.f;
    int   fin_b = 0, cnt = 0;
    bool  done = false;

    if (width > 0.f) {
        for (int level = 0; level < 4 && !done; ++level) {
            float scale = 128.0f / width;
            sHist[wv][lane] = 0u;
            sHist[wv][lane + 64] = 0u;
            asm volatile("s_waitcnt lgkmcnt(0)" ::: "memory");
            #pragma unroll
            for (int j = 0; j < TPL; ++j) {
                if (m_eq & (1u << j)) {
                    int idx = (int)((dd[j] - lo) * scale);   // cvt saturates; clamp below
                    idx = idx < 0 ? 0 : (idx > 127 ? 127 : idx);
                    atomicAdd(&sHist[wv][idx], 1u);
                }
            }
            asm volatile("s_waitcnt lgkmcnt(0)" ::: "memory");
            uint32_t v0 = sHist[wv][lane], v1 = sHist[wv][lane + 64];
            // inclusive prefix over 128 bins (two 64-lane scans)
            uint32_t c0 = v0;
            #pragma unroll
            for (int d2 = 1; d2 < 64; d2 <<= 1) { uint32_t y = __shfl_up(c0, d2, 64); if (lane >= d2) c0 += y; }
            uint32_t tot0 = __shfl(c0, 63, 64);
            uint32_t c1 = v1;
            #pragma unroll
            for (int d2 = 1; d2 < 64; d2 <<= 1) { uint32_t y = __shfl_up(c1, d2, 64); if (lane >= d2) c1 += y; }
            c1 += tot0;

            int T = 32 - c_less;   // invariant keeps 1 <= T <= 32
            uint64_t b0m = __ballot(c0 >= (uint32_t)T);
            uint64_t b1m = __ballot(c1 >= (uint32_t)T);
            int bstar = b0m ? (__ffsll((long long)b0m) - 1)
                            : 64 + (__ffsll((long long)b1m) - 1);
            bool hib = bstar >= 64;
            uint32_t cumB = __shfl(hib ? c1 : c0, bstar & 63, 64);
            uint32_t hB   = __shfl(hib ? v1 : v0, bstar & 63, 64);
            cnt = c_less + (int)cumB;
            if (cnt <= 64) {
                fin_lo = lo; fin_scale = scale; fin_b = bstar; done = true;
            } else {
                uint32_t nl = 0u, ne = 0u;
                #pragma unroll
                for (int j = 0; j < TPL; ++j) {
                    if (m_eq & (1u << j)) {
                        int idx = (int)((dd[j] - lo) * scale);
                        idx = idx < 0 ? 0 : (idx > 127 ? 127 : idx);
                        if (idx < bstar) nl |= (1u << j);
                        else if (idx == bstar) ne |= (1u << j);
                    }
                }
                m_less |= nl;
                m_eq = ne;
                c_less += (int)(cumB - hB);
                float binw = width / 128.0f;
                lo = lo + (float)bstar * binw;
                width = binw;
            }
        }
    }

    // ---- compaction of <=64 candidates into per-wave LDS (packed dist|idx).
    // Distances here are >= O(1) (min pairwise 4-D distance of this dataset),
    // so positive-f32 bit order == float order and raw bits sort correctly.
    if (done) {
        int base = 0;
        #pragma unroll
        for (int j = 0; j < TPL; ++j) {
            bool p = (m_less >> j) & 1u;
            if (!p && ((m_eq >> j) & 1u)) {
                int idx = (int)((dd[j] - fin_lo) * fin_scale);
                idx = idx < 0 ? 0 : (idx > 127 ? 127 : idx);
                p = (idx <= fin_b);
            }
            uint64_t mask = __ballot(p);
            if (p) {
                int pos = base + (int)__popcll(mask & ((1ull << lane) - 1ull));
                sC[wv][pos] = ((uint64_t)__float_as_uint(dd[j]) << 16) | (uint32_t)(j * 64 + lane);
            }
            base += (int)__popcll(mask);
        }
    } else {
        // exact bitwise binary search fallback (essentially never taken)
        uint32_t A = 0u; bool found = false; int ccf = 0;
        for (int b = 31; b >= 0; --b) {
            uint32_t T2 = A | ((1u << b) - 1u);
            int cc = 0;
            #pragma unroll
            for (int j = 0; j < TPL; ++j) cc += (f2key(dd[j]) <= T2) ? 1 : 0;
            #pragma unroll
            for (int m2 = 1; m2 < 64; m2 <<= 1) cc += __shfl_xor(cc, m2, 64);
            if (cc >= 32) { if (cc <= 64) { A = T2; ccf = cc; found = true; break; } }
            else A |= (1u << b);
        }
        if (!found) {
            int cc = 0;
            #pragma unroll
            for (int j = 0; j < TPL; ++j) cc += (f2key(dd[j]) <= A) ? 1 : 0;
            #pragma unroll
            for (int m2 = 1; m2 < 64; m2 <<= 1) cc += __shfl_xor(cc, m2, 64);
            ccf = cc;
        }
        cnt = ccf;
        int base = 0;
        #pragma unroll
        for (int j = 0; j < TPL; ++j) {
            bool p = (f2key(dd[j]) <= A);
            uint64_t mask = __ballot(p);
            if (p) {
                int pos = base + (int)__popcll(mask & ((1ull << lane) - 1ull));
                if (pos < 64)
                    sC[wv][pos] = ((uint64_t)__float_as_uint(dd[j]) << 16) | (uint32_t)(j * 64 + lane);
            }
            base += (int)__popcll(mask);
        }
    }
    int cnt_cap = cnt > 64 ? 64 : cnt;
    asm volatile("s_waitcnt lgkmcnt(0)" ::: "memory");

    // ---- bitonic sort of 64 candidates across lanes (ascending by (dist,idx));
    // lane l ends holding the l-th smallest -> slot l lives in lane l.
    uint64_t v = (lane < cnt_cap) ? sC[wv][lane] : ~0ull;
    #pragma unroll
    for (int k2 = 2; k2 <= 64; k2 <<= 1) {
        #pragma unroll
        for (int j2 = k2 >> 1; j2 >= 1; j2 >>= 1) {
            uint64_t o = __shfl_xor(v, j2, 64);
            bool dirAsc = ((lane & k2) == 0);
            bool lower  = ((lane & j2) == 0);
            uint64_t mn = (v < o) ? v : o;
            uint64_t mx = (v < o) ? o : v;
            v = (dirAsc == lower) ? mn : mx;
        }
    }

    // ---- gumbel-argmax over the 32 sorted slots (tie -> lower slot)
    float dsel = __uint_as_float((uint32_t)(v >> 16));
    int   tok  = (int)(v & 0xFFFFu);
    float score;
    int   slot = lane;
    if (lane < 32) {
        float neg   = -dsel;
        float logit = (-1e-6f) + neg;
        float g;
        if (useG) {
            g = gtab[(size_t)n * 32 + lane];
        } else {
            const float C1F = (float)(1.0 - 2.0 * 1e-7);
            float u = gumbel[(size_t)n * 32 + lane];
            float t = u * C1F;
            t = t + 1e-7f;
            float li = (float)log((double)t);
            float ni = -li;
            float lo2 = (float)log((double)ni);
            g = -lo2;
        }
        score = logit + g;
    } else {
        score = -INFINITY;
    }
    #pragma unroll
    for (int m2 = 1; m2 < 64; m2 <<= 1) {
        float so = __shfl_xor(score, m2, 64);
        int   sl = __shfl_xor(slot,  m2, 64);
        if (so > score || (so == score && sl < slot)) { score = so; slot = sl; }
    }
    int tw = __shfl(tok, slot, 64);

    if (lane < 22) out[(size_t)n * 22 + lane] = token_src[(size_t)tw * 22 + lane];
}

extern "C" void kernel_launch(void* const* d_in, const int* in_sizes, int n_in,
                              void* d_out, int out_size, void* d_ws, size_t ws_size,
                              hipStream_t stream) {
    const float* traj_pos   = (const float*)d_in[0];
    const float* traj_theta = (const float*)d_in[1];
    const float* mpt        = (const float*)d_in[2];
    const float* token_src  = (const float*)d_in[3];
    const float* gumbel     = (const float*)d_in[4];
    float* out = (float*)d_out;

    int N = in_sizes[0] / 6;

    // workspace layout
    size_t off_b4 = 0;                               // 2048 * 16B = 32 KB
    size_t off_sb = off_b4 + (size_t)K_TOK * 16;     // 8 KB
    size_t off_aA = off_sb + (size_t)K_TOK * 4;      // N * 16B = 1 MB
    size_t off_sa = off_aA + (size_t)N * 16;         // N * 4B = 256 KB
    size_t off_g  = off_sa + (size_t)N * 4;          // N * 32 * 4B = 8 MB
    size_t need_frame = off_sa + (size_t)N * 4;
    size_t need_g     = off_g + (size_t)N * 32 * 4;

    int useFrame = (ws_size >= need_frame) ? 1 : 0;
    int useG     = (ws_size >= need_g) ? 1 : 0;

    float4* b4  = (float4*)((char*)d_ws + off_b4);
    float*  sb  = (float*)((char*)d_ws + off_sb);
    float4* aA  = (float4*)((char*)d_ws + off_aA);
    float*  saA = (float*)((char*)d_ws + off_sa);
    float*  g   = (float*)((char*)d_ws + off_g);

    hipLaunchKernelGGL(prep_tok, dim3((K_TOK + 255) / 256), dim3(256), 0, stream, mpt, b4, sb);
    if (useFrame)
        hipLaunchKernelGGL(prep_frame, dim3((N + 255) / 256), dim3(256), 0, stream,
                           traj_pos, traj_theta, aA, saA, N);
    if (useG) {
        int total = N * 32;
        hipLaunchKernelGGL(prep_gumbel, dim3((total + 255) / 256), dim3(256), 0, stream,
                           gumbel, g, total);
    }

    int blocks = (N + WPB - 1) / WPB;
    hipLaunchKernelGGL(topk_kernel, dim3(blocks), dim3(BLK), 0, stream,
                       traj_pos, traj_theta, b4, sb, aA, saA, g,
                       token_src, gumbel, out, N, useFrame, useG);
}

// Round 3
// 164.803 us; speedup vs baseline: 3.2180x; 3.2180x over previous
//
#include <hip/hip_runtime.h>
#include <cstdint>
#include <math.h>

#define K_TOK 2048
#define TPL   32      // tokens per lane (K_TOK / 64)
#define BLK   512
#define WPB   8       // waves (=rows) per block

// monotonic float->uint key (total order == float order, handles negatives)
__device__ __forceinline__ uint32_t f2key(float f) {
    uint32_t u = __float_as_uint(f);
    return u ^ ((uint32_t)(((int32_t)u) >> 31) | 0x80000000u);
}
__device__ __forceinline__ float key2f(uint32_t k) {
    uint32_t m = ((uint32_t)((~(int32_t)k) >> 31)) | 0x80000000u;
    return __uint_as_float(k ^ m);
}

// ---------------- prep kernels (validated bit-exact in R1/R2) ----------------
__global__ void prep_tok(const float* __restrict__ mpt,
                         float4* __restrict__ b4out, float* __restrict__ sbout) {
    #pragma clang fp contract(off)
    int k = blockIdx.x * blockDim.x + threadIdx.x;
    if (k >= K_TOK) return;
    float b0 = mpt[k*6+0], b1 = mpt[k*6+1], b2 = mpt[k*6+2];
    float b3 = mpt[k*6+3], b4 = mpt[k*6+4], b5 = mpt[k*6+5];
    float q0=b0*b0,q1=b1*b1,q2=b2*b2,q3=b3*b3,q4=b4*b4,q5=b5*b5;
    float s = ((((q0+q1)+q2)+q3)+q4)+q5;   // sequential, no fma
    b4out[k] = make_float4(b2,b3,b4,b5);
    sbout[k] = s;
}

__global__ void prep_frame(const float* __restrict__ traj_pos,
                           const float* __restrict__ traj_theta,
                           float4* __restrict__ aA, float* __restrict__ saA, int N) {
    #pragma clang fp contract(off)
    int n = blockIdx.x * blockDim.x + threadIdx.x;
    if (n >= N) return;
    const float* tp = traj_pos + (size_t)n*6;
    float p0x=tp[0], p0y=tp[1];
    float dx1=tp[2]-p0x, dy1=tp[3]-p0y;
    float dx2=tp[4]-p0x, dy2=tp[5]-p0y;
    float th = traj_theta[n];
    float c = (float)cos((double)th);
    float s = (float)sin((double)th);
    float ns = -s;
    float a2 = c*dx1 + s*dy1;
    float a3 = ns*dx1 + c*dy1;
    float a4 = c*dx2 + s*dy2;
    float a5 = ns*dx2 + c*dy2;
    float q2=a2*a2,q3=a3*a3,q4=a4*a4,q5=a5*a5;
    float sa = ((q2+q3)+q4)+q5;
    aA[n] = make_float4(a2,a3,a4,a5);
    saA[n] = sa;
}

__global__ void prep_gumbel(const float* __restrict__ gu, float* __restrict__ g, int total) {
    #pragma clang fp contract(off)
    int i = blockIdx.x * blockDim.x + threadIdx.x;
    if (i >= total) return;
    const float C1F = (float)(1.0 - 2.0*1e-7);
    float u = gu[i];
    float t = u * C1F;
    t = t + 1e-7f;
    float li = (float)log((double)t);
    float ni = -li;
    float lo = (float)log((double)ni);
    g[i] = -lo;
}

// wave-wide count of dd[j] <= T
__device__ __forceinline__ int count_le(const float dd[TPL], float T) {
    int c = 0;
    #pragma unroll
    for (int j = 0; j < TPL; ++j) c += (dd[j] <= T) ? 1 : 0;
    #pragma unroll
    for (int m = 1; m < 64; m <<= 1) c += __shfl_xor(c, m, 64);
    return c;
}

// ---------------- main kernel ----------------
__global__ __launch_bounds__(BLK) void topk_kernel(
        const float* __restrict__ traj_pos, const float* __restrict__ traj_theta,
        const float4* __restrict__ b4g, const float* __restrict__ sbg,
        const float4* __restrict__ aAg, const float* __restrict__ saAg,
        const float* __restrict__ gtab,
        const float* __restrict__ token_src, const float* __restrict__ gumbel,
        float* __restrict__ out, int Nrows, int useFrame, int useG) {
    #pragma clang fp contract(off)
    __shared__ float4   sB4[K_TOK];
    __shared__ float    sSB[K_TOK];
    __shared__ uint64_t sC[WPB][64];

    const int tid = threadIdx.x;
    for (int t = tid; t < K_TOK; t += BLK) { sB4[t] = b4g[t]; sSB[t] = sbg[t]; }
    __syncthreads();

    const int wv   = tid >> 6;
    const int lane = tid & 63;
    const int n    = blockIdx.x * WPB + wv;
    if (n >= Nrows) return;

    // ---- per-row local frame
    float a2, a3, a4, a5, sa;
    if (useFrame) {
        float4 av = aAg[n];
        a2 = av.x; a3 = av.y; a4 = av.z; a5 = av.w;
        sa = saAg[n];
    } else {
        const float* tp = traj_pos + (size_t)n * 6;
        float p0x = tp[0], p0y = tp[1];
        float dx1 = tp[2] - p0x, dy1 = tp[3] - p0y;
        float dx2 = tp[4] - p0x, dy2 = tp[5] - p0y;
        float th = traj_theta[n];
        float c = (float)cos((double)th);
        float s = (float)sin((double)th);
        float ns = -s;
        a2 = c*dx1 + s*dy1;
        a3 = ns*dx1 + c*dy1;
        a4 = c*dx2 + s*dy2;
        a5 = ns*dx2 + c*dy2;
        float q2 = a2*a2, q3 = a3*a3, q4 = a4*a4, q5 = a5*a5;
        sa = ((q2 + q3) + q4) + q5;
    }

    // ---- distances (exact reference rounding), per-lane min
    float dd[TPL];
    float lmin;
    #pragma unroll
    for (int j = 0; j < TPL; ++j) {
        int t = j * 64 + lane;
        float4 b = sB4[t];
        float sbv = sSB[t];
        float d0 = a2 * b.x;
        d0 = fmaf(a3, b.y, d0);
        d0 = fmaf(a4, b.z, d0);
        d0 = fmaf(a5, b.w, d0);
        float t2 = 2.0f * d0;
        float dist = (sa + sbv) - t2;
        dd[j] = dist;
        lmin = (j == 0) ? dist : fminf(lmin, dist);
    }

    // ---- bitonic ascending sort of lane minima across 64 lanes.
    // After sorting, lane i holds the (i+1)-th smallest lane-min.
    {
        float v = lmin;
        #pragma unroll
        for (int k2 = 2; k2 <= 64; k2 <<= 1) {
            #pragma unroll
            for (int j2 = k2 >> 1; j2 >= 1; j2 >>= 1) {
                float o = __shfl_xor(v, j2, 64);
                bool up = ((lane & k2) == 0) == ((lane & j2) == 0);
                v = up ? fminf(v, o) : fmaxf(v, o);
            }
        }
        lmin = v;  // reuse: sorted order-stat in lane index
    }
    float gmn = __shfl(lmin, 0, 64);
    float T0  = __shfl(lmin, 31, 64);  // 32 lanes have min <= T0 -> count >= 32

    // ---- find threshold T with count(d <= T) in [32,64]
    float T = T0;
    int cnt = count_le(dd, T);
    bool done = (cnt >= 32 && cnt <= 64);
    float loV = gmn, hiV = T0;
    for (int it = 0; it < 12 && !done; ++it) {
        float mid = 0.5f * (loV + hiV);
        if (!(mid > loV && mid < hiV)) break;   // interval collapsed
        int c = count_le(dd, mid);
        if (c < 32) loV = mid;
        else if (c > 64) hiV = mid;
        else { T = mid; cnt = c; done = true; }
    }

    uint32_t cmask = 0;
    if (done) {
        #pragma unroll
        for (int j = 0; j < TPL; ++j) if (dd[j] <= T) cmask |= (1u << j);
    } else {
        // exact bitwise binary search on monotone keys (cold, provably correct)
        uint32_t A = 0u; bool found = false; int ccf = 0;
        for (int b = 31; b >= 0; --b) {
            uint32_t T2 = A | ((1u << b) - 1u);
            int cc = 0;
            #pragma unroll
            for (int j = 0; j < TPL; ++j) cc += (f2key(dd[j]) <= T2) ? 1 : 0;
            #pragma unroll
            for (int m2 = 1; m2 < 64; m2 <<= 1) cc += __shfl_xor(cc, m2, 64);
            if (cc >= 32) { if (cc <= 64) { A = T2; ccf = cc; found = true; break; } }
            else A |= (1u << b);
        }
        if (!found) {
            int cc = 0;
            #pragma unroll
            for (int j = 0; j < TPL; ++j) cc += (f2key(dd[j]) <= A) ? 1 : 0;
            #pragma unroll
            for (int m2 = 1; m2 < 64; m2 <<= 1) cc += __shfl_xor(cc, m2, 64);
            ccf = cc;
        }
        cnt = ccf;
        #pragma unroll
        for (int j = 0; j < TPL; ++j) if (f2key(dd[j]) <= A) cmask |= (1u << j);
    }
    int cnt_cap = cnt > 64 ? 64 : cnt;

    // ---- compaction via prefix-sum (order irrelevant; exact sort follows)
    {
        int lc = __popc(cmask);
        int pre = lc;
        #pragma unroll
        for (int d2 = 1; d2 < 64; d2 <<= 1) {
            int y = __shfl_up(pre, d2, 64);
            if (lane >= d2) pre += y;
        }
        int pos = pre - lc;  // exclusive prefix
        #pragma unroll
        for (int j = 0; j < TPL; ++j) {
            if ((cmask >> j) & 1u) {
                if (pos < 64)
                    sC[wv][pos] = ((uint64_t)f2key(dd[j]) << 16) | (uint32_t)(j * 64 + lane);
                ++pos;
            }
        }
    }
    asm volatile("s_waitcnt lgkmcnt(0)" ::: "memory");

    // ---- bitonic sort of 64 candidates across lanes, ascending (key,idx);
    // lane l ends holding slot l (the l-th smallest).
    uint64_t bv = (lane < cnt_cap) ? sC[wv][lane] : ~0ull;
    #pragma unroll
    for (int k2 = 2; k2 <= 64; k2 <<= 1) {
        #pragma unroll
        for (int j2 = k2 >> 1; j2 >= 1; j2 >>= 1) {
            uint64_t o = __shfl_xor(bv, j2, 64);
            bool up = ((lane & k2) == 0) == ((lane & j2) == 0);
            uint64_t mn = (bv < o) ? bv : o;
            uint64_t mx = (bv < o) ? o : bv;
            bv = up ? mn : mx;
        }
    }

    // ---- gumbel-argmax over the 32 sorted slots (tie -> lower slot)
    float dsel = key2f((uint32_t)(bv >> 16));
    int   tok  = (int)(bv & 0xFFFFu);
    float score;
    int   slot = lane;
    if (lane < 32) {
        float neg   = -dsel;
        float logit = (-1e-6f) + neg;
        float g;
        if (useG) {
            g = gtab[(size_t)n * 32 + lane];
        } else {
            const float C1F = (float)(1.0 - 2.0 * 1e-7);
            float u = gumbel[(size_t)n * 32 + lane];
            float t = u * C1F;
            t = t + 1e-7f;
            float li = (float)log((double)t);
            float ni = -li;
            float lo2 = (float)log((double)ni);
            g = -lo2;
        }
        score = logit + g;
    } else {
        score = -INFINITY;
    }
    #pragma unroll
    for (int m2 = 1; m2 < 64; m2 <<= 1) {
        float so = __shfl_xor(score, m2, 64);
        int   sl = __shfl_xor(slot,  m2, 64);
        if (so > score || (so == score && sl < slot)) { score = so; slot = sl; }
    }
    int tw = __shfl(tok, slot, 64);

    if (lane < 22) out[(size_t)n * 22 + lane] = token_src[(size_t)tw * 22 + lane];
}

extern "C" void kernel_launch(void* const* d_in, const int* in_sizes, int n_in,
                              void* d_out, int out_size, void* d_ws, size_t ws_size,
                              hipStream_t stream) {
    const float* traj_pos   = (const float*)d_in[0];
    const float* traj_theta = (const float*)d_in[1];
    const float* mpt        = (const float*)d_in[2];
    const float* token_src  = (const float*)d_in[3];
    const float* gumbel     = (const float*)d_in[4];
    float* out = (float*)d_out;

    int N = in_sizes[0] / 6;

    size_t off_b4 = 0;                               // 32 KB
    size_t off_sb = off_b4 + (size_t)K_TOK * 16;     // 8 KB
    size_t off_aA = off_sb + (size_t)K_TOK * 4;      // N*16
    size_t off_sa = off_aA + (size_t)N * 16;         // N*4
    size_t off_g  = off_sa + (size_t)N * 4;          // N*32*4
    size_t need_frame = off_sa + (size_t)N * 4;
    size_t need_g     = off_g + (size_t)N * 32 * 4;

    int useFrame = (ws_size >= need_frame) ? 1 : 0;
    int useG     = (ws_size >= need_g) ? 1 : 0;

    float4* b4  = (float4*)((char*)d_ws + off_b4);
    float*  sb  = (float*)((char*)d_ws + off_sb);
    float4* aA  = (float4*)((char*)d_ws + off_aA);
    float*  saA = (float*)((char*)d_ws + off_sa);
    float*  g   = (float*)((char*)d_ws + off_g);

    hipLaunchKernelGGL(prep_tok, dim3((K_TOK + 255) / 256), dim3(256), 0, stream, mpt, b4, sb);
    if (useFrame)
        hipLaunchKernelGGL(prep_frame, dim3((N + 255) / 256), dim3(256), 0, stream,
                           traj_pos, traj_theta, aA, saA, N);
    if (useG) {
        int total = N * 32;
        hipLaunchKernelGGL(prep_gumbel, dim3((total + 255) / 256), dim3(256), 0, stream,
                           gumbel, g, total);
    }

    int blocks = (N + WPB - 1) / WPB;
    hipLaunchKernelGGL(topk_kernel, dim3(blocks), dim3(BLK), 0, stream,
                       traj_pos, traj_theta, b4, sb, aA, saA, g,
                       token_src, gumbel, out, N, useFrame, useG);
}

// Round 5
// 150.453 us; speedup vs baseline: 3.5249x; 1.0954x over previous
//
#include <hip/hip_runtime.h>
#include <cstdint>
#include <math.h>

#define K_TOK 2048
#define TPL   32      // tokens per lane (K_TOK / 64)
#define BLK   512
#define WPB   8       // waves (=rows) per block

// monotonic float->uint key (total order == float order, handles negatives)
__device__ __forceinline__ uint32_t f2key(float f) {
    uint32_t u = __float_as_uint(f);
    return u ^ ((uint32_t)(((int32_t)u) >> 31) | 0x80000000u);
}
__device__ __forceinline__ float key2f(uint32_t k) {
    uint32_t m = ((uint32_t)((~(int32_t)k) >> 31)) | 0x80000000u;
    return __uint_as_float(k ^ m);
}

// ---------------- DPP wave64 primitives (ctrl args must be constexpr) ----------------
template<int CTRL, int RM, int BM, bool BC>
__device__ __forceinline__ int dpp_i(int old, int v) {
    return __builtin_amdgcn_update_dpp(old, v, CTRL, RM, BM, BC);
}
// full-wave sum -> wave-uniform scalar (rocPRIM cascade)
__device__ __forceinline__ int wave_sum(int v) {
    v += dpp_i<0x111, 0xf, 0xf, true >(0, v);   // row_shr:1
    v += dpp_i<0x112, 0xf, 0xf, true >(0, v);   // row_shr:2
    v += dpp_i<0x114, 0xf, 0xf, true >(0, v);   // row_shr:4
    v += dpp_i<0x118, 0xf, 0xf, true >(0, v);   // row_shr:8
    v += dpp_i<0x142, 0xa, 0xf, false>(0, v);   // row_bcast15 -> rows 1,3
    v += dpp_i<0x143, 0xc, 0xf, false>(0, v);   // row_bcast31 -> rows 2,3
    return __builtin_amdgcn_readlane(v, 63);
}
// inclusive wave scan (Hillis-Steele via DPP), all lanes active
__device__ __forceinline__ int wave_scan_incl(int v) {
    v += dpp_i<0x111, 0xf, 0xf, true >(0, v);
    v += dpp_i<0x112, 0xf, 0xf, true >(0, v);
    v += dpp_i<0x114, 0xf, 0xf, true >(0, v);
    v += dpp_i<0x118, 0xf, 0xf, true >(0, v);
    v += dpp_i<0x142, 0xa, 0xf, false>(0, v);
    v += dpp_i<0x143, 0xc, 0xf, false>(0, v);
    return v;
}
// lane-xor exchange: DPP for 1,2,8; ds_swizzle for 4,16; bpermute for 32
template<int M>
__device__ __forceinline__ uint32_t lxu(uint32_t x) {
    if constexpr (M == 1)       return (uint32_t)dpp_i<0xB1,  0xf, 0xf, true>(0, (int)x);   // quad_perm 1,0,3,2
    else if constexpr (M == 2)  return (uint32_t)dpp_i<0x4E,  0xf, 0xf, true>(0, (int)x);   // quad_perm 2,3,0,1
    else if constexpr (M == 8)  return (uint32_t)dpp_i<0x128, 0xf, 0xf, true>(0, (int)x);   // row_ror:8 == xor8 (row=16)
    else if constexpr (M == 4)  return (uint32_t)__builtin_amdgcn_ds_swizzle((int)x, 0x101F);
    else if constexpr (M == 16) return (uint32_t)__builtin_amdgcn_ds_swizzle((int)x, 0x401F);
    else                        return (uint32_t)__shfl_xor((int)x, 32, 64);
}
template<int M>
__device__ __forceinline__ uint64_t lxu64(uint64_t x) {
    uint32_t h = lxu<M>((uint32_t)(x >> 32));
    uint32_t l = lxu<M>((uint32_t)x);
    return ((uint64_t)h << 32) | l;
}

// ---------------- prep kernels (validated bit-exact R1-R3) ----------------
__global__ void prep_tok(const float* __restrict__ mpt,
                         float4* __restrict__ b4out, float* __restrict__ sbout) {
    #pragma clang fp contract(off)
    int k = blockIdx.x * blockDim.x + threadIdx.x;
    if (k >= K_TOK) return;
    float b0 = mpt[k*6+0], b1 = mpt[k*6+1], b2 = mpt[k*6+2];
    float b3 = mpt[k*6+3], b4 = mpt[k*6+4], b5 = mpt[k*6+5];
    float q0=b0*b0,q1=b1*b1,q2=b2*b2,q3=b3*b3,q4=b4*b4,q5=b5*b5;
    float s = ((((q0+q1)+q2)+q3)+q4)+q5;
    b4out[k] = make_float4(b2,b3,b4,b5);
    sbout[k] = s;
}

__global__ void prep_frame(const float* __restrict__ traj_pos,
                           const float* __restrict__ traj_theta,
                           float4* __restrict__ aA, float* __restrict__ saA, int N) {
    #pragma clang fp contract(off)
    int n = blockIdx.x * blockDim.x + threadIdx.x;
    if (n >= N) return;
    const float* tp = traj_pos + (size_t)n*6;
    float p0x=tp[0], p0y=tp[1];
    float dx1=tp[2]-p0x, dy1=tp[3]-p0y;
    float dx2=tp[4]-p0x, dy2=tp[5]-p0y;
    float th = traj_theta[n];
    float c = (float)cos((double)th);
    float s = (float)sin((double)th);
    float ns = -s;
    float a2 = c*dx1 + s*dy1;
    float a3 = ns*dx1 + c*dy1;
    float a4 = c*dx2 + s*dy2;
    float a5 = ns*dx2 + c*dy2;
    float q2=a2*a2,q3=a3*a3,q4=a4*a4,q5=a5*a5;
    float sa = ((q2+q3)+q4)+q5;
    aA[n] = make_float4(a2,a3,a4,a5);
    saA[n] = sa;
}

__global__ void prep_gumbel(const float* __restrict__ gu, float* __restrict__ g, int total) {
    #pragma clang fp contract(off)
    int i = blockIdx.x * blockDim.x + threadIdx.x;
    if (i >= total) return;
    const float C1F = (float)(1.0 - 2.0*1e-7);
    float u = gu[i];
    float t = u * C1F;
    t = t + 1e-7f;
    float li = (float)log((double)t);
    float ni = -li;
    float lo = (float)log((double)ni);
    g[i] = -lo;
}

// build candidate mask (dd[j] <= T) and wave count; predicate identical to R3
__device__ __forceinline__ int count_mask(const float dd[TPL], float T, uint32_t* cmo) {
    uint32_t cm = 0;
    #pragma unroll
    for (int j = 0; j < TPL; ++j) cm |= (dd[j] <= T) ? (1u << j) : 0u;
    *cmo = cm;
    return wave_sum(__popc(cm));
}

// ---------------- main kernel ----------------
__global__ __launch_bounds__(BLK, 4) void topk_kernel(
        const float* __restrict__ traj_pos, const float* __restrict__ traj_theta,
        const float4* __restrict__ b4g, const float* __restrict__ sbg,
        const float4* __restrict__ aAg, const float* __restrict__ saAg,
        const float* __restrict__ gtab,
        const float* __restrict__ token_src, const float* __restrict__ gumbel,
        float* __restrict__ out, int Nrows, int useFrame, int useG) {
    #pragma clang fp contract(off)
    __shared__ float    sSB[K_TOK];            // 8 KB
    __shared__ uint64_t sC[WPB][64];           // 4 KB

    const int tid = threadIdx.x;
    {   // stage only sSB (B4 comes from L1/L2 via global loads)
        const float4* s4 = (const float4*)sbg;
        ((float4*)sSB)[tid] = s4[tid];         // 512 * 16B = 8 KB
    }
    __syncthreads();

    const int wv   = tid >> 6;
    const int lane = tid & 63;
    const int n    = blockIdx.x * WPB + wv;
    if (n >= Nrows) return;

    // ---- per-row local frame
    float a2, a3, a4, a5, sa;
    if (useFrame) {
        float4 av = aAg[n];
        a2 = av.x; a3 = av.y; a4 = av.z; a5 = av.w;
        sa = saAg[n];
    } else {
        const float* tp = traj_pos + (size_t)n * 6;
        float p0x = tp[0], p0y = tp[1];
        float dx1 = tp[2] - p0x, dy1 = tp[3] - p0y;
        float dx2 = tp[4] - p0x, dy2 = tp[5] - p0y;
        float th = traj_theta[n];
        float c = (float)cos((double)th);
        float s = (float)sin((double)th);
        float ns = -s;
        a2 = c*dx1 + s*dy1;
        a3 = ns*dx1 + c*dy1;
        a4 = c*dx2 + s*dy2;
        a5 = ns*dx2 + c*dy2;
        float q2 = a2*a2, q3 = a3*a3, q4 = a4*a4, q5 = a5*a5;
        sa = ((q2 + q3) + q4) + q5;
    }

    // ---- distances (exact reference rounding): B4 from global, sb from LDS
    float dd[TPL];
    float lmin = INFINITY;
    #pragma unroll
    for (int j = 0; j < TPL; ++j) {
        int t = j * 64 + lane;
        float4 b = b4g[t];
        float sbv = sSB[t];
        float d0 = a2 * b.x;
        d0 = fmaf(a3, b.y, d0);
        d0 = fmaf(a4, b.z, d0);
        d0 = fmaf(a5, b.w, d0);
        float t2 = 2.0f * d0;
        float dist = (sa + sbv) - t2;
        dd[j] = dist;
        lmin = fminf(lmin, dist);
    }

    // ---- bitonic ascending sort of lane minima (values identical to R3)
    {
        float v = lmin;
        #define FST(K2,J2) { float o = __uint_as_float(lxu<J2>(__float_as_uint(v))); \
            bool up = ((lane & K2) == 0) == ((lane & J2) == 0); \
            v = up ? fminf(v, o) : fmaxf(v, o); }
        FST(2,1)
        FST(4,2)  FST(4,1)
        FST(8,4)  FST(8,2)  FST(8,1)
        FST(16,8) FST(16,4) FST(16,2) FST(16,1)
        FST(32,16) FST(32,8) FST(32,4) FST(32,2) FST(32,1)
        FST(64,32) FST(64,16) FST(64,8) FST(64,4) FST(64,2) FST(64,1)
        #undef FST
        lmin = v;
    }
    float gmn = __uint_as_float((uint32_t)__builtin_amdgcn_readlane((int)__float_as_uint(lmin), 0));
    float T0  = __uint_as_float((uint32_t)__builtin_amdgcn_readlane((int)__float_as_uint(lmin), 31));

    // ---- threshold with count(d <= T) in [32,64]  (logic identical to R3)
    uint32_t cmask = 0;
    int cnt = count_mask(dd, T0, &cmask);
    bool done = (cnt >= 32 && cnt <= 64);
    float loV = gmn, hiV = T0;
    for (int it = 0; it < 12 && !done; ++it) {
        float mid = 0.5f * (loV + hiV);
        if (!(mid > loV && mid < hiV)) break;
        uint32_t cm2;
        int c = count_mask(dd, mid, &cm2);
        if (c < 32) loV = mid;
        else if (c > 64) hiV = mid;
        else { cnt = c; cmask = cm2; done = true; }
    }

    if (!done) {
        // exact bitwise binary search fallback (cold, provably correct)
        uint32_t A = 0u; bool found = false; int ccf = 0;
        for (int b = 31; b >= 0; --b) {
            uint32_t T2 = A | ((1u << b) - 1u);
            int cc = 0;
            #pragma unroll
            for (int j = 0; j < TPL; ++j) cc += (f2key(dd[j]) <= T2) ? 1 : 0;
            cc = wave_sum(cc);
            if (cc >= 32) { if (cc <= 64) { A = T2; ccf = cc; found = true; break; } }
            else A |= (1u << b);
        }
        if (!found) {
            int cc = 0;
            #pragma unroll
            for (int j = 0; j < TPL; ++j) cc += (f2key(dd[j]) <= A) ? 1 : 0;
            ccf = wave_sum(cc);
        }
        cnt = ccf;
        cmask = 0;
        #pragma unroll
        for (int j = 0; j < TPL; ++j) if (f2key(dd[j]) <= A) cmask |= (1u << j);
    }
    int cnt_cap = cnt > 64 ? 64 : cnt;

    // ---- compaction via DPP prefix-scan (set identical to count predicate)
    {
        int lc  = __popc(cmask);
        int pos = wave_scan_incl(lc) - lc;   // exclusive prefix
        #pragma unroll
        for (int j = 0; j < TPL; ++j) {
            if ((cmask >> j) & 1u) {
                if (pos < 64)
                    sC[wv][pos] = ((uint64_t)f2key(dd[j]) << 16) | (uint32_t)(j * 64 + lane);
                ++pos;
            }
        }
    }
    asm volatile("s_waitcnt lgkmcnt(0)" ::: "memory");

    // ---- bitonic sort of 64 candidates, ascending (key,idx); slot l in lane l
    uint64_t bv = (lane < cnt_cap) ? sC[wv][lane] : ~0ull;
    #define UST(K2,J2) { uint64_t o = lxu64<J2>(bv); \
        bool up = ((lane & K2) == 0) == ((lane & J2) == 0); \
        uint64_t mn = (bv < o) ? bv : o; \
        uint64_t mx = (bv < o) ? o : bv; \
        bv = up ? mn : mx; }
    UST(2,1)
    UST(4,2)  UST(4,1)
    UST(8,4)  UST(8,2)  UST(8,1)
    UST(16,8) UST(16,4) UST(16,2) UST(16,1)
    UST(32,16) UST(32,8) UST(32,4) UST(32,2) UST(32,1)
    UST(64,32) UST(64,16) UST(64,8) UST(64,4) UST(64,2) UST(64,1)
    #undef UST

    // ---- gumbel-argmax over 32 sorted slots (tie -> lower slot), DPP max-reduce
    float dsel = key2f((uint32_t)(bv >> 16));
    int   tok  = (int)(bv & 0xFFFFu);
    uint32_t kh = 0u, kl = 0u;
    if (lane < 32) {
        float neg   = -dsel;
        float logit = (-1e-6f) + neg;
        float g;
        if (useG) {
            g = gtab[(size_t)n * 32 + lane];
        } else {
            const float C1F = (float)(1.0 - 2.0 * 1e-7);
            float u = gumbel[(size_t)n * 32 + lane];
            float t = u * C1F;
            t = t + 1e-7f;
            float li = (float)log((double)t);
            float ni = -li;
            float lo2 = (float)log((double)ni);
            g = -lo2;
        }
        float score = logit + g;
        kh = f2key(score);
        kl = ((uint32_t)(63 - lane) << 11) | (uint32_t)tok;  // tie -> lower slot wins
    }
    // 64-bit max-reduce via DPP on both halves (packed (kh,kl) monotone key)
    #define MAXST(CTRL, RM) { \
        uint32_t oh = (uint32_t)dpp_i<CTRL, RM, 0xf, false>((int)kh, (int)kh); \
        uint32_t ol = (uint32_t)dpp_i<CTRL, RM, 0xf, false>((int)kl, (int)kl); \
        if (((((uint64_t)oh << 32) | ol)) > ((((uint64_t)kh << 32) | kl))) { kh = oh; kl = ol; } }
    MAXST(0x111, 0xf) MAXST(0x112, 0xf) MAXST(0x114, 0xf) MAXST(0x118, 0xf)
    MAXST(0x142, 0xa) MAXST(0x143, 0xc)
    #undef MAXST
    uint32_t wl = (uint32_t)__builtin_amdgcn_readlane((int)kl, 63);
    int tw = (int)(wl & 0x7FFu);

    if (lane < 22) out[(size_t)n * 22 + lane] = token_src[(size_t)tw * 22 + lane];
}

extern "C" void kernel_launch(void* const* d_in, const int* in_sizes, int n_in,
                              void* d_out, int out_size, void* d_ws, size_t ws_size,
                              hipStream_t stream) {
    const float* traj_pos   = (const float*)d_in[0];
    const float* traj_theta = (const float*)d_in[1];
    const float* mpt        = (const float*)d_in[2];
    const float* token_src  = (const float*)d_in[3];
    const float* gumbel     = (const float*)d_in[4];
    float* out = (float*)d_out;

    int N = in_sizes[0] / 6;

    size_t off_b4 = 0;                               // 32 KB
    size_t off_sb = off_b4 + (size_t)K_TOK * 16;     // 8 KB
    size_t off_aA = off_sb + (size_t)K_TOK * 4;      // N*16
    size_t off_sa = off_aA + (size_t)N * 16;         // N*4
    size_t off_g  = off_sa + (size_t)N * 4;          // N*32*4
    size_t need_frame = off_sa + (size_t)N * 4;
    size_t need_g     = off_g + (size_t)N * 32 * 4;

    int useFrame = (ws_size >= need_frame) ? 1 : 0;
    int useG     = (ws_size >= need_g) ? 1 : 0;

    float4* b4  = (float4*)((char*)d_ws + off_b4);
    float*  sb  = (float*)((char*)d_ws + off_sb);
    float4* aA  = (float4*)((char*)d_ws + off_aA);
    float*  saA = (float*)((char*)d_ws + off_sa);
    float*  g   = (float*)((char*)d_ws + off_g);

    hipLaunchKernelGGL(prep_tok, dim3((K_TOK + 255) / 256), dim3(256), 0, stream, mpt, b4, sb);
    if (useFrame)
        hipLaunchKernelGGL(prep_frame, dim3((N + 255) / 256), dim3(256), 0, stream,
                           traj_pos, traj_theta, aA, saA, N);
    if (useG) {
        int total = N * 32;
        hipLaunchKernelGGL(prep_gumbel, dim3((total + 255) / 256), dim3(256), 0, stream,
                           gumbel, g, total);
    }

    int blocks = (N + WPB - 1) / WPB;
    hipLaunchKernelGGL(topk_kernel, dim3(blocks), dim3(BLK), 0, stream,
                       traj_pos, traj_theta, b4, sb, aA, saA, g,
                       token_src, gumbel, out, N, useFrame, useG);
}

// Round 6
// 107.577 us; speedup vs baseline: 4.9299x; 1.3986x over previous
//
#include <hip/hip_runtime.h>
#include <cstdint>
#include <math.h>

#define K_TOK 2048
#define NPAIR 16      // token pairs per lane (K_TOK / 2 / 64)
#define BLK   512
#define WPB   8       // waves (=rows) per block

typedef float v2f __attribute__((ext_vector_type(2)));

// monotonic float->uint key (total order == float order, handles negatives)
__device__ __forceinline__ uint32_t f2key(float f) {
    uint32_t u = __float_as_uint(f);
    return u ^ ((uint32_t)(((int32_t)u) >> 31) | 0x80000000u);
}

// ---------------- DPP wave64 primitives (ctrl args constexpr) ----------------
template<int CTRL, int RM, int BM, bool BC>
__device__ __forceinline__ int dpp_i(int old, int v) {
    return __builtin_amdgcn_update_dpp(old, v, CTRL, RM, BM, BC);
}
__device__ __forceinline__ int wave_sum(int v) {
    v += dpp_i<0x111, 0xf, 0xf, true >(0, v);
    v += dpp_i<0x112, 0xf, 0xf, true >(0, v);
    v += dpp_i<0x114, 0xf, 0xf, true >(0, v);
    v += dpp_i<0x118, 0xf, 0xf, true >(0, v);
    v += dpp_i<0x142, 0xa, 0xf, false>(0, v);
    v += dpp_i<0x143, 0xc, 0xf, false>(0, v);
    return __builtin_amdgcn_readlane(v, 63);
}
__device__ __forceinline__ int wave_scan_incl(int v) {
    v += dpp_i<0x111, 0xf, 0xf, true >(0, v);
    v += dpp_i<0x112, 0xf, 0xf, true >(0, v);
    v += dpp_i<0x114, 0xf, 0xf, true >(0, v);
    v += dpp_i<0x118, 0xf, 0xf, true >(0, v);
    v += dpp_i<0x142, 0xa, 0xf, false>(0, v);
    v += dpp_i<0x143, 0xc, 0xf, false>(0, v);
    return v;
}
template<int M>
__device__ __forceinline__ uint32_t lxu(uint32_t x) {
    if constexpr (M == 1)       return (uint32_t)dpp_i<0xB1,  0xf, 0xf, true>(0, (int)x);
    else if constexpr (M == 2)  return (uint32_t)dpp_i<0x4E,  0xf, 0xf, true>(0, (int)x);
    else if constexpr (M == 8)  return (uint32_t)dpp_i<0x128, 0xf, 0xf, true>(0, (int)x);
    else if constexpr (M == 4)  return (uint32_t)__builtin_amdgcn_ds_swizzle((int)x, 0x101F);
    else if constexpr (M == 16) return (uint32_t)__builtin_amdgcn_ds_swizzle((int)x, 0x401F);
    else                        return (uint32_t)__shfl_xor((int)x, 32, 64);
}
template<int M>
__device__ __forceinline__ uint64_t lxu64(uint64_t x) {
    uint32_t h = lxu<M>((uint32_t)(x >> 32));
    uint32_t l = lxu<M>((uint32_t)x);
    return ((uint64_t)h << 32) | l;
}

// ---------------- prep kernels ----------------
// Pair-interleaved B: bpair[2P] = {b2[2P],b2[2P+1],b3[2P],b3[2P+1]},
//                     bpair[2P+1] = {b4[2P],b4[2P+1],b5[2P],b5[2P+1]}
__global__ void prep_tok(const float* __restrict__ mpt,
                         float4* __restrict__ bpair, float* __restrict__ sbout) {
    #pragma clang fp contract(off)
    int P = blockIdx.x * blockDim.x + threadIdx.x;
    if (P >= K_TOK / 2) return;
    int k0 = 2 * P, k1 = 2 * P + 1;
    float u0 = mpt[k0*6+0], u1 = mpt[k0*6+1], u2 = mpt[k0*6+2];
    float u3 = mpt[k0*6+3], u4 = mpt[k0*6+4], u5 = mpt[k0*6+5];
    float w0 = mpt[k1*6+0], w1 = mpt[k1*6+1], w2 = mpt[k1*6+2];
    float w3 = mpt[k1*6+3], w4 = mpt[k1*6+4], w5 = mpt[k1*6+5];
    float s0 = ((((u0*u0+u1*u1)+u2*u2)+u3*u3)+u4*u4)+u5*u5;
    float s1 = ((((w0*w0+w1*w1)+w2*w2)+w3*w3)+w4*w4)+w5*w5;
    bpair[2*P]   = make_float4(u2, w2, u3, w3);
    bpair[2*P+1] = make_float4(u4, w4, u5, w5);
    sbout[k0] = s0; sbout[k1] = s1;
}

__global__ void prep_frame(const float* __restrict__ traj_pos,
                           const float* __restrict__ traj_theta,
                           float4* __restrict__ aA, float* __restrict__ saA, int N) {
    #pragma clang fp contract(off)
    int n = blockIdx.x * blockDim.x + threadIdx.x;
    if (n >= N) return;
    const float* tp = traj_pos + (size_t)n*6;
    float p0x=tp[0], p0y=tp[1];
    float dx1=tp[2]-p0x, dy1=tp[3]-p0y;
    float dx2=tp[4]-p0x, dy2=tp[5]-p0y;
    float th = traj_theta[n];
    float c = (float)cos((double)th);
    float s = (float)sin((double)th);
    float ns = -s;
    float a2 = c*dx1 + s*dy1;
    float a3 = ns*dx1 + c*dy1;
    float a4 = c*dx2 + s*dy2;
    float a5 = ns*dx2 + c*dy2;
    float q2=a2*a2,q3=a3*a3,q4=a4*a4,q5=a5*a5;
    float sa = ((q2+q3)+q4)+q5;
    aA[n] = make_float4(a2,a3,a4,a5);
    saA[n] = sa;
}

__global__ void prep_gumbel(const float* __restrict__ gu, float* __restrict__ g, int total) {
    #pragma clang fp contract(off)
    int i = blockIdx.x * blockDim.x + threadIdx.x;
    if (i >= total) return;
    const float C1F = (float)(1.0 - 2.0*1e-7);
    float u = gu[i];
    float t = u * C1F;
    t = t + 1e-7f;
    float li = (float)log((double)t);
    float ni = -li;
    float lo = (float)log((double)ni);
    g[i] = -lo;
}

// candidate mask over pairs + wave count (predicate identical to R3/R5)
__device__ __forceinline__ int count_mask(const v2f dd2[NPAIR], float T, uint32_t* cmo) {
    uint32_t cm = 0;
    #pragma unroll
    for (int p = 0; p < NPAIR; ++p) {
        if (dd2[p].x <= T) cm |= (1u << (2*p));
        if (dd2[p].y <= T) cm |= (1u << (2*p+1));
    }
    *cmo = cm;
    return wave_sum(__popc(cm));
}

// ---------------- main kernel ----------------
__global__ __launch_bounds__(BLK, 4) void topk_kernel(
        const float* __restrict__ traj_pos, const float* __restrict__ traj_theta,
        const float4* __restrict__ bpair, const float* __restrict__ sbg,
        const float4* __restrict__ aAg, const float* __restrict__ saAg,
        const float* __restrict__ gtab,
        const float* __restrict__ token_src, const float* __restrict__ gumbel,
        float* __restrict__ out, int Nrows, int useFrame, int useG) {
    #pragma clang fp contract(off)
    __shared__ float    sSB[K_TOK];            // 8 KB
    __shared__ uint32_t sCidx[WPB][64];        // 2 KB

    const int tid = threadIdx.x;
    {
        const float4* s4 = (const float4*)sbg;
        ((float4*)sSB)[tid] = s4[tid];         // 8 KB staged
    }
    __syncthreads();

    const int wv   = tid >> 6;
    const int lane = tid & 63;
    const int n    = blockIdx.x * WPB + wv;
    if (n >= Nrows) return;

    // ---- per-row local frame
    float a2, a3, a4, a5, sa;
    if (useFrame) {
        float4 av = aAg[n];
        a2 = av.x; a3 = av.y; a4 = av.z; a5 = av.w;
        sa = saAg[n];
    } else {
        const float* tp = traj_pos + (size_t)n * 6;
        float p0x = tp[0], p0y = tp[1];
        float dx1 = tp[2] - p0x, dy1 = tp[3] - p0y;
        float dx2 = tp[4] - p0x, dy2 = tp[5] - p0y;
        float th = traj_theta[n];
        float c = (float)cos((double)th);
        float s = (float)sin((double)th);
        float ns = -s;
        a2 = c*dx1 + s*dy1;
        a3 = ns*dx1 + c*dy1;
        a4 = c*dx2 + s*dy2;
        a5 = ns*dx2 + c*dy2;
        float q2 = a2*a2, q3 = a3*a3, q4 = a4*a4, q5 = a5*a5;
        sa = ((q2 + q3) + q4) + q5;
    }

    // ---- packed distances (per-component rounding == validated scalar chain)
    const v2f a2v = { a2, a2 }, a3v = { a3, a3 }, a4v = { a4, a4 }, a5v = { a5, a5 };
    const v2f sav = { sa, sa }, n2v = { -2.0f, -2.0f };
    v2f dd2[NPAIR];
    v2f lm2 = { INFINITY, INFINITY };
    #pragma unroll
    for (int p = 0; p < NPAIR; ++p) {
        int P = p * 64 + lane;
        float4 q0 = bpair[2*P];
        float4 q1 = bpair[2*P+1];
        v2f sb2 = ((const v2f*)sSB)[P];
        v2f bx = { q0.x, q0.y }, by = { q0.z, q0.w };
        v2f bz = { q1.x, q1.y }, bw = { q1.z, q1.w };
        v2f d = a2v * bx;                              // pk_mul
        d = __builtin_elementwise_fma(a3v, by, d);     // pk_fma
        d = __builtin_elementwise_fma(a4v, bz, d);
        d = __builtin_elementwise_fma(a5v, bw, d);
        v2f ss = sav + sb2;                            // pk_add
        v2f dist = __builtin_elementwise_fma(n2v, d, ss);  // == (sa+sb) - 2*d0 bitwise
        dd2[p] = dist;
        lm2.x = fminf(lm2.x, dist.x);
        lm2.y = fminf(lm2.y, dist.y);
    }
    float lmin = fminf(lm2.x, lm2.y);

    // ---- bitonic ascending sort of lane minima (T0 = 31st order stat)
    {
        float v = lmin;
        #define FST(K2,J2) { float o = __uint_as_float(lxu<J2>(__float_as_uint(v))); \
            bool up = ((lane & K2) == 0) == ((lane & J2) == 0); \
            v = up ? fminf(v, o) : fmaxf(v, o); }
        FST(2,1)
        FST(4,2)  FST(4,1)
        FST(8,4)  FST(8,2)  FST(8,1)
        FST(16,8) FST(16,4) FST(16,2) FST(16,1)
        FST(32,16) FST(32,8) FST(32,4) FST(32,2) FST(32,1)
        FST(64,32) FST(64,16) FST(64,8) FST(64,4) FST(64,2) FST(64,1)
        #undef FST
        lmin = v;
    }
    float gmn = __uint_as_float((uint32_t)__builtin_amdgcn_readlane((int)__float_as_uint(lmin), 0));
    float T0  = __uint_as_float((uint32_t)__builtin_amdgcn_readlane((int)__float_as_uint(lmin), 31));

    // ---- threshold with count(d <= T) in [32,64]
    uint32_t cmask = 0;
    int cnt = count_mask(dd2, T0, &cmask);
    bool done = (cnt >= 32 && cnt <= 64);
    float loV = gmn, hiV = T0;
    for (int it = 0; it < 12 && !done; ++it) {
        float mid = 0.5f * (loV + hiV);
        if (!(mid > loV && mid < hiV)) break;
        uint32_t cm2;
        int c = count_mask(dd2, mid, &cm2);
        if (c < 32) loV = mid;
        else if (c > 64) hiV = mid;
        else { cnt = c; cmask = cm2; done = true; }
    }

    if (!done) {
        // exact bitwise binary search fallback (cold, provably correct)
        uint32_t A = 0u; bool found = false; int ccf = 0;
        for (int b = 31; b >= 0; --b) {
            uint32_t T2 = A | ((1u << b) - 1u);
            int cc = 0;
            #pragma unroll
            for (int p = 0; p < NPAIR; ++p) {
                cc += (f2key(dd2[p].x) <= T2) ? 1 : 0;
                cc += (f2key(dd2[p].y) <= T2) ? 1 : 0;
            }
            cc = wave_sum(cc);
            if (cc >= 32) { if (cc <= 64) { A = T2; ccf = cc; found = true; break; } }
            else A |= (1u << b);
        }
        if (!found) {
            int cc = 0;
            #pragma unroll
            for (int p = 0; p < NPAIR; ++p) {
                cc += (f2key(dd2[p].x) <= A) ? 1 : 0;
                cc += (f2key(dd2[p].y) <= A) ? 1 : 0;
            }
            ccf = wave_sum(cc);
        }
        cnt = ccf;
        cmask = 0;
        #pragma unroll
        for (int p = 0; p < NPAIR; ++p) {
            if (f2key(dd2[p].x) <= A) cmask |= (1u << (2*p));
            if (f2key(dd2[p].y) <= A) cmask |= (1u << (2*p+1));
        }
    }
    int cnt_cap = cnt > 64 ? 64 : cnt;

    // ---- sparse compaction: store token INDEX only (E[iters/lane] ~ 0.7)
    {
        int lc  = __popc(cmask);
        int pos = wave_scan_incl(lc) - lc;   // exclusive prefix
        uint32_t m = cmask;
        while (m) {
            int j = __builtin_ctz(m);
            m &= m - 1;
            int token = 2 * ((j >> 1) * 64 + lane) + (j & 1);
            if (pos < 64) sCidx[wv][pos] = (uint32_t)token;
            ++pos;
        }
    }
    asm volatile("s_waitcnt lgkmcnt(0)" ::: "memory");

    // ---- read back + exact recompute (identical op sequence -> identical bits)
    uint64_t bv;
    if (lane < cnt_cap) {
        uint32_t idxv = sCidx[wv][lane];
        uint32_t P = idxv >> 1;
        float4 q0 = bpair[2*P];
        float4 q1 = bpair[2*P+1];
        int h = (int)(idxv & 1u);
        float bx = h ? q0.y : q0.x;
        float by = h ? q0.w : q0.z;
        float bz = h ? q1.y : q1.x;
        float bw = h ? q1.w : q1.z;
        float sbv = sSB[idxv];
        float d0 = a2 * bx;
        d0 = fmaf(a3, by, d0);
        d0 = fmaf(a4, bz, d0);
        d0 = fmaf(a5, bw, d0);
        float ss = sa + sbv;
        float dist = fmaf(-2.0f, d0, ss);
        bv = ((uint64_t)f2key(dist) << 16) | (uint64_t)idxv;
    } else {
        bv = ~0ull;
    }

    // ---- bitonic sort of 64 candidates, ascending (key,idx); slot l -> lane l
    #define UST(K2,J2) { uint64_t o = lxu64<J2>(bv); \
        bool up = ((lane & K2) == 0) == ((lane & J2) == 0); \
        bv = ((o < bv) == up) ? o : bv; }
    UST(2,1)
    UST(4,2)  UST(4,1)
    UST(8,4)  UST(8,2)  UST(8,1)
    UST(16,8) UST(16,4) UST(16,2) UST(16,1)
    UST(32,16) UST(32,8) UST(32,4) UST(32,2) UST(32,1)
    UST(64,32) UST(64,16) UST(64,8) UST(64,4) UST(64,2) UST(64,1)
    #undef UST

    // ---- gumbel-argmax over 32 sorted slots (tie -> lower slot)
    float dsel;
    {
        uint32_t kbits = (uint32_t)(bv >> 16);
        uint32_t mkb = ((uint32_t)((~(int32_t)kbits) >> 31)) | 0x80000000u;
        dsel = __uint_as_float(kbits ^ mkb);
    }
    int tok = (int)(bv & 0xFFFFu);
    uint32_t kh = 0u, kl = 0u;
    if (lane < 32) {
        float neg   = -dsel;
        float logit = (-1e-6f) + neg;
        float g;
        if (useG) {
            g = gtab[(size_t)n * 32 + lane];
        } else {
            const float C1F = (float)(1.0 - 2.0 * 1e-7);
            float u = gumbel[(size_t)n * 32 + lane];
            float t = u * C1F;
            t = t + 1e-7f;
            float li = (float)log((double)t);
            float ni = -li;
            float lo2 = (float)log((double)ni);
            g = -lo2;
        }
        float score = logit + g;
        kh = f2key(score);
        kl = ((uint32_t)(63 - lane) << 11) | (uint32_t)tok;  // tie -> lower slot
    }
    #define MAXST(CTRL, RM) { \
        uint32_t oh = (uint32_t)dpp_i<CTRL, RM, 0xf, false>((int)kh, (int)kh); \
        uint32_t ol = (uint32_t)dpp_i<CTRL, RM, 0xf, false>((int)kl, (int)kl); \
        if (((((uint64_t)oh << 32) | ol)) > ((((uint64_t)kh << 32) | kl))) { kh = oh; kl = ol; } }
    MAXST(0x111, 0xf) MAXST(0x112, 0xf) MAXST(0x114, 0xf) MAXST(0x118, 0xf)
    MAXST(0x142, 0xa) MAXST(0x143, 0xc)
    #undef MAXST
    uint32_t wl = (uint32_t)__builtin_amdgcn_readlane((int)kl, 63);
    int tw = (int)(wl & 0x7FFu);

    if (lane < 22) out[(size_t)n * 22 + lane] = token_src[(size_t)tw * 22 + lane];
}

extern "C" void kernel_launch(void* const* d_in, const int* in_sizes, int n_in,
                              void* d_out, int out_size, void* d_ws, size_t ws_size,
                              hipStream_t stream) {
    const float* traj_pos   = (const float*)d_in[0];
    const float* traj_theta = (const float*)d_in[1];
    const float* mpt        = (const float*)d_in[2];
    const float* token_src  = (const float*)d_in[3];
    const float* gumbel     = (const float*)d_in[4];
    float* out = (float*)d_out;

    int N = in_sizes[0] / 6;

    size_t off_bp = 0;                               // 2048 float4 = 32 KB
    size_t off_sb = off_bp + (size_t)K_TOK * 16;     // 8 KB
    size_t off_aA = off_sb + (size_t)K_TOK * 4;      // N*16
    size_t off_sa = off_aA + (size_t)N * 16;         // N*4
    size_t off_g  = off_sa + (size_t)N * 4;          // N*32*4
    size_t need_frame = off_sa + (size_t)N * 4;
    size_t need_g     = off_g + (size_t)N * 32 * 4;

    int useFrame = (ws_size >= need_frame) ? 1 : 0;
    int useG     = (ws_size >= need_g) ? 1 : 0;

    float4* bp  = (float4*)((char*)d_ws + off_bp);
    float*  sb  = (float*)((char*)d_ws + off_sb);
    float4* aA  = (float4*)((char*)d_ws + off_aA);
    float*  saA = (float*)((char*)d_ws + off_sa);
    float*  g   = (float*)((char*)d_ws + off_g);

    hipLaunchKernelGGL(prep_tok, dim3((K_TOK/2 + 255) / 256), dim3(256), 0, stream, mpt, bp, sb);
    if (useFrame)
        hipLaunchKernelGGL(prep_frame, dim3((N + 255) / 256), dim3(256), 0, stream,
                           traj_pos, traj_theta, aA, saA, N);
    if (useG) {
        int total = N * 32;
        hipLaunchKernelGGL(prep_gumbel, dim3((total + 255) / 256), dim3(256), 0, stream,
                           gumbel, g, total);
    }

    int blocks = (N + WPB - 1) / WPB;
    hipLaunchKernelGGL(topk_kernel, dim3(blocks), dim3(BLK), 0, stream,
                       traj_pos, traj_theta, bp, sb, aA, saA, g,
                       token_src, gumbel, out, N, useFrame, useG);
}